// Round 6
// baseline (528.838 us; speedup 1.0000x reference)
//
#include <hip/hip_runtime.h>

// ---------------- problem constants ----------------
#define S_   2048
#define DM   512
#define HD   64
#define BHN  32

typedef unsigned short u16;
typedef __bf16 bf16x8 __attribute__((ext_vector_type(8)));
typedef float  f32x4  __attribute__((ext_vector_type(4)));

__device__ __forceinline__ float bf2f(u16 u) {
    union { unsigned int i; float f; } v; v.i = ((unsigned int)u) << 16; return v.f;
}
__device__ __forceinline__ u16 f2bf(float f) {
    union { float f; unsigned int i; } v; v.f = f;
    unsigned int i = v.i;
    return (u16)((i + 0x7FFFu + ((i >> 16) & 1u)) >> 16);   // RNE
}
// RNE 3-term split (used for Q only — pass B consumes fq0 alone, RNE halves
// its single-term error; this is the accuracy wall that sets absmax).
__device__ __forceinline__ void split3(float x, u16& b0, u16& b1, u16& b2) {
    b0 = f2bf(x);
    const float r0 = x - bf2f(b0);
    b1 = f2bf(r0);
    const float r1 = r0 - bf2f(b1);
    b2 = f2bf(r1);
}
// Truncation 3-term split: EXACT (x == b0+b1+b2) and ~3x fewer VALU ops.
__device__ __forceinline__ void split3t(float x, u16& b0, u16& b1, u16& b2) {
    union { float f; unsigned int i; } v; v.f = x;
    const unsigned int i0 = v.i & 0xFFFF0000u;
    b0 = (u16)(i0 >> 16);
    union { float f; unsigned int i; } w0c; w0c.i = i0;
    const float r0 = x - w0c.f;
    union { float f; unsigned int i; } u; u.f = r0;
    const unsigned int i1 = u.i & 0xFFFF0000u;
    b1 = (u16)(i1 >> 16);
    union { float f; unsigned int i; } w1c; w1c.i = i1;
    const float r1 = r0 - w1c.f;
    union { float f; unsigned int i; } z; z.f = r1;
    b2 = (u16)(z.i >> 16);
}

// ---------------- prep: W[k][n] fp32 -> transposed bf16 splits [n][k] ----------------
__global__ __launch_bounds__(256) void prep_split_wT(
    const float* __restrict__ W, int N, int total,
    u16* __restrict__ w0, u16* __restrict__ w1, u16* __restrict__ w2)
{
    for (int idx = blockIdx.x * 256 + threadIdx.x; idx < total; idx += gridDim.x * 256) {
        const int n = idx >> 9, k = idx & 511;      // K = 512
        u16 a0, a1, a2;
        split3t(W[(size_t)k * N + n], a0, a1, a2);
        w0[idx] = a0; w1[idx] = a1;
        if (w2) w2[idx] = a2;
    }
}

// ---------------- QKV GEMM: MFMA, 3-split x, 3-split W^T ----------------
// K is written twice: fp32 (for pass-A splits + band refine) and RNE bf16
// (khi, consumed directly by pass-B staging — bit-identical to the f2bf pass B
// used to compute per-tile, hoisted here so it's done once instead of 16x/bh).
__global__ __launch_bounds__(256) void gemm_qkv_mfma(
    const float* __restrict__ A, const u16* __restrict__ Wt0, const u16* __restrict__ Wt1,
    const u16* __restrict__ Wt2, const float* __restrict__ bias,
    float* __restrict__ qh, float* __restrict__ kh, u16* __restrict__ khi,
    u16* __restrict__ vt)
{
    __shared__ __attribute__((aligned(16))) u16 As0[128 * 32], As1[128 * 32], As2[128 * 32];
    __shared__ __attribute__((aligned(16))) u16 Bs0[128 * 32], Bs1[128 * 32], Bs2[128 * 32];

    const int t  = threadIdx.x;
    const int m0 = blockIdx.y * 128, n0 = blockIdx.x * 128;
    const int w  = t >> 6, l = t & 63;
    const int wm = (w >> 1) * 64, wn = (w & 1) * 64;
    const int lr = l & 15, lq = l >> 4;

    const f32x4 zero4 = {0.f, 0.f, 0.f, 0.f};
    f32x4 acc[4][4];
#pragma unroll
    for (int i = 0; i < 4; i++)
#pragma unroll
        for (int j = 0; j < 4; j++) acc[i][j] = zero4;

    for (int k0 = 0; k0 < 512; k0 += 32) {
        __syncthreads();
#pragma unroll
        for (int i = 0; i < 4; i++) {
            const int e = t + 256 * i;
            const int r = e >> 3, c4 = (e & 7) * 4;
            const float4 f = *(const float4*)(&A[(size_t)(m0 + r) * 512 + k0 + c4]);
            const float xv[4] = {f.x, f.y, f.z, f.w};
            u16 a0[4], a1[4], a2[4];
#pragma unroll
            for (int j = 0; j < 4; j++) split3t(xv[j], a0[j], a1[j], a2[j]);
            int2 p0, p1, p2;
            p0.x = a0[0] | (a0[1] << 16); p0.y = a0[2] | (a0[3] << 16);
            p1.x = a1[0] | (a1[1] << 16); p1.y = a1[2] | (a1[3] << 16);
            p2.x = a2[0] | (a2[1] << 16); p2.y = a2[2] | (a2[3] << 16);
            *(int2*)(&As0[r * 32 + c4]) = p0;
            *(int2*)(&As1[r * 32 + c4]) = p1;
            *(int2*)(&As2[r * 32 + c4]) = p2;
        }
#pragma unroll
        for (int i = 0; i < 2; i++) {
            const int e = t + 256 * i;
            const int r = e >> 2, c0 = (e & 3) * 8;
            *(int4*)(&Bs0[r * 32 + c0]) = *(const int4*)(&Wt0[(size_t)(n0 + r) * 512 + k0 + c0]);
            *(int4*)(&Bs1[r * 32 + c0]) = *(const int4*)(&Wt1[(size_t)(n0 + r) * 512 + k0 + c0]);
            *(int4*)(&Bs2[r * 32 + c0]) = *(const int4*)(&Wt2[(size_t)(n0 + r) * 512 + k0 + c0]);
        }
        __syncthreads();

#pragma unroll
        for (int i = 0; i < 4; i++) {
            const int ao = (wm + i * 16 + lr) * 32 + lq * 8;
            const bf16x8 a0 = *(const bf16x8*)(&As0[ao]);
            const bf16x8 a1 = *(const bf16x8*)(&As1[ao]);
            const bf16x8 a2 = *(const bf16x8*)(&As2[ao]);
#pragma unroll
            for (int j = 0; j < 4; j++) {
                const int bo = (wn + j * 16 + lr) * 32 + lq * 8;
                const bf16x8 b0 = *(const bf16x8*)(&Bs0[bo]);
                const bf16x8 b1 = *(const bf16x8*)(&Bs1[bo]);
                const bf16x8 b2 = *(const bf16x8*)(&Bs2[bo]);
                f32x4 c = acc[i][j];
                c = __builtin_amdgcn_mfma_f32_16x16x32_bf16(a0, b0, c, 0, 0, 0);
                c = __builtin_amdgcn_mfma_f32_16x16x32_bf16(a0, b1, c, 0, 0, 0);
                c = __builtin_amdgcn_mfma_f32_16x16x32_bf16(a1, b0, c, 0, 0, 0);
                c = __builtin_amdgcn_mfma_f32_16x16x32_bf16(a1, b1, c, 0, 0, 0);
                c = __builtin_amdgcn_mfma_f32_16x16x32_bf16(a0, b2, c, 0, 0, 0);
                c = __builtin_amdgcn_mfma_f32_16x16x32_bf16(a2, b0, c, 0, 0, 0);
                acc[i][j] = c;
            }
        }
    }

#pragma unroll
    for (int j = 0; j < 4; j++) {
        const int n = n0 + wn + j * 16 + lr;
        const float bv = bias[n];
        const int part = n >> 9, within = n & 511;
        const int h = within >> 6, d = within & 63;
#pragma unroll
        for (int i = 0; i < 4; i++) {
#pragma unroll
            for (int r = 0; r < 4; r++) {
                const int m = m0 + wm + i * 16 + lq * 4 + r;
                const int b = m >> 11, ns = m & 2047;
                const float val = acc[i][j][r] + bv;
                if (part == 0) {
                    qh[(((size_t)(b * 8 + h)) * S_ + ns) * HD + d] = val;
                } else if (part == 1) {
                    const size_t kidx = (((size_t)(b * 8 + h)) * S_ + ns) * HD + d;
                    kh[kidx]  = val;
                    khi[kidx] = f2bf(val);
                } else {
                    vt[(((size_t)(b * 8 + h)) * HD + d) * S_ + ns] = f2bf(val);
                }
            }
        }
    }
}

// ---------------- attention: 128 q-rows/block, 8 waves (16 rows/wave) ----------------
// R5 structure + T14 async-STAGE (VGPR=60 gave headroom R2 lacked): next jt's
// global loads issue right after the post-staging barrier and land in regs;
// the ds_write at the next iteration's top is a pure reg->LDS copy. Pass-B K
// staging now reads precomputed RNE bf16 (khi): 8KB copy, no conversion.
#define LDH 72

__global__ __launch_bounds__(512) void attn_mfma128(
    const float* __restrict__ q_ws, const float* __restrict__ k_ws,
    const u16* __restrict__ khi_ws, const u16* __restrict__ vt_ws,
    u16* __restrict__ ao_ws)
{
    __shared__ __attribute__((aligned(16))) u16 K0s[64 * LDH], K1s[64 * LDH], K2s[64 * LDH];
    __shared__ __attribute__((aligned(16))) u16 Vs[64 * LDH];
    __shared__ __attribute__((aligned(16))) u16 Ps[8][16 * LDH];
    __shared__ float smaxL[8][32];

    const int t  = threadIdx.x;
    const int w  = t >> 6, l = t & 63;
    const int lr = l & 15, lq = l >> 4;
    const int bh = blockIdx.y, b = bh >> 3, h = bh & 7;
    const int q0 = blockIdx.x * 128;

    const float* qg  = q_ws + ((size_t)bh * S_ + q0) * HD;
    const float* kg0 = k_ws + (size_t)bh * S_ * HD;
    const u16*   kh0 = khi_ws + (size_t)bh * S_ * HD;
    const u16*   vb  = vt_ws + (size_t)bh * HD * S_;

    // ---- stage Q 3-split (scale folded) in two 64-row halves through K buffers ----
    bf16x8 fq0[2], fq1[2], fq2[2];    // [kc]
#pragma unroll
    for (int h2 = 0; h2 < 2; h2++) {
        __syncthreads();
#pragma unroll
        for (int i = 0; i < 2; i++) {
            const int e = t + 512 * i;                 // 1024 float4s over 64x64
            const int row = e >> 4, c0 = (e & 15) * 4;
            const float4 f = *(const float4*)(qg + (size_t)h2 * 4096 + (size_t)e * 4);
            const float xv[4] = {f.x * 0.125f, f.y * 0.125f, f.z * 0.125f, f.w * 0.125f};
            u16 a0[4], a1[4], a2[4];
#pragma unroll
            for (int j = 0; j < 4; j++) split3(xv[j], a0[j], a1[j], a2[j]);
            int2 p0, p1, p2;
            p0.x = a0[0] | (a0[1] << 16); p0.y = a0[2] | (a0[3] << 16);
            p1.x = a1[0] | (a1[1] << 16); p1.y = a1[2] | (a1[3] << 16);
            p2.x = a2[0] | (a2[1] << 16); p2.y = a2[2] | (a2[3] << 16);
            *(int2*)(&K0s[row * LDH + c0]) = p0;
            *(int2*)(&K1s[row * LDH + c0]) = p1;
            *(int2*)(&K2s[row * LDH + c0]) = p2;
        }
        __syncthreads();
        if ((w >> 2) == h2) {
#pragma unroll
            for (int kc = 0; kc < 2; kc++) {
                const int o = ((w & 3) * 16 + lr) * LDH + kc * 32 + lq * 8;
                fq0[kc] = *(const bf16x8*)(&K0s[o]);
                fq1[kc] = *(const bf16x8*)(&K1s[o]);
                fq2[kc] = *(const bf16x8*)(&K2s[o]);
            }
        }
    }

    const f32x4 zero4 = {0.f, 0.f, 0.f, 0.f};
    double lsum[4];
#pragma unroll
    for (int r = 0; r < 4; r++) lsum[r] = 0.0;

    // ---- pass A: denominator via 3-split scores, prefetched staging ----
    float4 ka[2];
#pragma unroll
    for (int i = 0; i < 2; i++)
        ka[i] = *(const float4*)(kg0 + (size_t)(t + 512 * i) * 4);   // tile 0

    for (int jt = 0; jt < 32; jt++) {
        __syncthreads();
#pragma unroll
        for (int i = 0; i < 2; i++) {
            const int e = t + 512 * i;
            const int row = e >> 4, c0 = (e & 15) * 4;
            const float4 f = ka[i];
            const float xv[4] = {f.x, f.y, f.z, f.w};
            u16 a0[4], a1[4], a2[4];
#pragma unroll
            for (int j = 0; j < 4; j++) split3t(xv[j], a0[j], a1[j], a2[j]);
            int2 p0, p1, p2;
            p0.x = a0[0] | (a0[1] << 16); p0.y = a0[2] | (a0[3] << 16);
            p1.x = a1[0] | (a1[1] << 16); p1.y = a1[2] | (a1[3] << 16);
            p2.x = a2[0] | (a2[1] << 16); p2.y = a2[2] | (a2[3] << 16);
            *(int2*)(&K0s[row * LDH + c0]) = p0;
            *(int2*)(&K1s[row * LDH + c0]) = p1;
            *(int2*)(&K2s[row * LDH + c0]) = p2;
        }
        __syncthreads();

        // issue next tile's loads; latency hides under MFMA+exp below
        {
            const int jn = (jt + 1 < 32) ? jt + 1 : 31;
            const float* kg = kg0 + (size_t)jn * 64 * HD;
#pragma unroll
            for (int i = 0; i < 2; i++)
                ka[i] = *(const float4*)(kg + (size_t)(t + 512 * i) * 4);
        }

        float tmax = -1e30f;
#pragma unroll
        for (int nt = 0; nt < 4; nt++) {
            f32x4 aHH = zero4, aC = zero4;
#pragma unroll
            for (int kc = 0; kc < 2; kc++) {
                const int ko = (nt * 16 + lr) * LDH + kc * 32 + lq * 8;
                const bf16x8 k0 = *(const bf16x8*)(&K0s[ko]);
                const bf16x8 k1 = *(const bf16x8*)(&K1s[ko]);
                const bf16x8 k2 = *(const bf16x8*)(&K2s[ko]);
                aHH = __builtin_amdgcn_mfma_f32_16x16x32_bf16(fq0[kc], k0, aHH, 0, 0, 0);
                aC  = __builtin_amdgcn_mfma_f32_16x16x32_bf16(fq0[kc], k1, aC, 0, 0, 0);
                aC  = __builtin_amdgcn_mfma_f32_16x16x32_bf16(fq1[kc], k0, aC, 0, 0, 0);
                aC  = __builtin_amdgcn_mfma_f32_16x16x32_bf16(fq1[kc], k1, aC, 0, 0, 0);
                aC  = __builtin_amdgcn_mfma_f32_16x16x32_bf16(fq0[kc], k2, aC, 0, 0, 0);
                aC  = __builtin_amdgcn_mfma_f32_16x16x32_bf16(fq2[kc], k0, aC, 0, 0, 0);
            }
#pragma unroll
            for (int r = 0; r < 4; r++) {
                const float s = fminf(fmaxf(aHH[r] + aC[r], -30.f), 30.f);
                tmax = fmaxf(tmax, s);
                lsum[r] += (double)__expf(s);
            }
        }
        // wave-tile max of the ACCURATE scores -> LDS (read in pass B for skip)
#pragma unroll
        for (int off = 1; off < 64; off <<= 1)
            tmax = fmaxf(tmax, __shfl_xor(tmax, off, 64));
        if (l == 0) smaxL[w][jt] = tmax;
    }
#pragma unroll
    for (int r = 0; r < 4; r++) {
#pragma unroll
        for (int off = 1; off < 16; off <<= 1)
            lsum[r] += __shfl_xor(lsum[r], off, 64);
    }
    double l_d[4]; float inv_l[4];
#pragma unroll
    for (int r = 0; r < 4; r++) {
        l_d[r] = lsum[r];
        inv_l[r] = (float)(1.0 / lsum[r]);
    }

    // skip threshold: tile all-zero iff smax < ln(0.0085 * min-row-Z)
    float zmin4 = (float)fmin(fmin(lsum[0], lsum[1]), fmin(lsum[2], lsum[3]));
    zmin4 = fminf(zmin4, __shfl_xor(zmin4, 16, 64));
    zmin4 = fminf(zmin4, __shfl_xor(zmin4, 32, 64));
    const float sthr = logf(0.0085f * zmin4);

    f32x4 oacc[4];
#pragma unroll
    for (int dt = 0; dt < 4; dt++) oacc[dt] = zero4;

    // ---- pass B: bf16 scores, band [0.009,0.0115] -> fp64 refine, MFMA PV ----
    int4 kb, vr;
    kb = *(const int4*)(&kh0[(size_t)(t >> 3) * HD + (t & 7) * 8]);           // tile 0 K-hi
    vr = *(const int4*)(&vb[(size_t)(t >> 3) * S_ + (t & 7) * 8]);            // tile 0 V

    for (int jt = 0; jt < 32; jt++) {
        __syncthreads();
        {
            const int row = t >> 3, c0 = (t & 7) * 8;
            *(int4*)(&K0s[row * LDH + c0]) = kb;    // 64x64 bf16 K-hi, pure copy
            *(int4*)(&Vs[row * LDH + c0])  = vr;    // V^T tile [d][key]
        }
        __syncthreads();

        // issue next tile's loads — hide under score/PV compute
        {
            const int jn = (jt + 1 < 32) ? jt + 1 : 31;
            const int row = t >> 3, c0 = (t & 7) * 8;
            kb = *(const int4*)(&kh0[(size_t)jn * 64 * HD + (size_t)row * HD + c0]);
            vr = *(const int4*)(&vb[(size_t)row * S_ + jn * 64 + c0]);
        }

        const bool live = (smaxL[w][jt] >= sthr);   // wave-uniform branch

        if (live) {
#pragma unroll
            for (int nt = 0; nt < 4; nt++) {
                f32x4 sacc = zero4;
#pragma unroll
                for (int kc = 0; kc < 2; kc++) {
                    const bf16x8 k0 = *(const bf16x8*)(&K0s[(nt * 16 + lr) * LDH + kc * 32 + lq * 8]);
                    sacc = __builtin_amdgcn_mfma_f32_16x16x32_bf16(fq0[kc], k0, sacc, 0, 0, 0);
                }
#pragma unroll
                for (int r = 0; r < 4; r++) {
                    const float s = fminf(fmaxf(sacc[r], -30.f), 30.f);
                    const float p = __expf(s) * inv_l[r];
                    u16 pb;
                    if (p > 0.0115f) {
                        pb = f2bf(p);
                    } else if (p < 0.009f) {
                        pb = 0;
                    } else {
                        const int row = q0 + w * 16 + lq * 4 + r;
                        const int col = jt * 64 + nt * 16 + lr;
                        const float* qr  = q_ws + ((size_t)bh * S_ + row) * HD;
                        const float* kcv = k_ws + ((size_t)bh * S_ + col) * HD;
                        double s64 = 0.0;
                        for (int d = 0; d < HD; d++) s64 += (double)qr[d] * (double)kcv[d];
                        s64 = fmin(fmax(s64 * 0.125, -30.0), 30.0);
                        const double pd = exp(s64) / l_d[r];
                        pb = (pd > 0.01) ? f2bf((float)pd) : (u16)0;
                    }
                    Ps[w][(lq * 4 + r) * LDH + nt * 16 + lr] = pb;
                }
            }
        }
        __syncthreads();   // P stores -> P b128 reads (TBAA fence); all waves rendezvous
        if (live) {
#pragma unroll
            for (int kc = 0; kc < 2; kc++) {
                const bf16x8 ap = *(const bf16x8*)(&Ps[w][lr * LDH + kc * 32 + lq * 8]);
#pragma unroll
                for (int dt = 0; dt < 4; dt++) {
                    const bf16x8 bv = *(const bf16x8*)(&Vs[(dt * 16 + lr) * LDH + kc * 32 + lq * 8]);
                    oacc[dt] = __builtin_amdgcn_mfma_f32_16x16x32_bf16(ap, bv, oacc[dt], 0, 0, 0);
                }
            }
        }
        // no trailing barrier: next jt's two staging barriers separate these Ps/Vs
        // reads from any overwrite.
    }

    // epilogue
#pragma unroll
    for (int dt = 0; dt < 4; dt++) {
#pragma unroll
        for (int r = 0; r < 4; r++) {
            const int row = q0 + w * 16 + lq * 4 + r;
            const int d   = dt * 16 + lr;
            ao_ws[((size_t)b * S_ + row) * DM + h * HD + d] = f2bf(oacc[dt][r]);
        }
    }
}

// ---------------- out projection: MFMA, bf16 A x 2-split W^T -> fp32 out ----------------
__global__ __launch_bounds__(256) void gemm_out_mfma(
    const u16* __restrict__ A, const u16* __restrict__ Wt0, const u16* __restrict__ Wt1,
    const float* __restrict__ bias, float* __restrict__ out)
{
    __shared__ __attribute__((aligned(16))) u16 As[128 * 32];
    __shared__ __attribute__((aligned(16))) u16 Bs0[128 * 32], Bs1[128 * 32];

    const int t  = threadIdx.x;
    const int m0 = blockIdx.y * 128, n0 = blockIdx.x * 128;
    const int w  = t >> 6, l = t & 63;
    const int wm = (w >> 1) * 64, wn = (w & 1) * 64;
    const int lr = l & 15, lq = l >> 4;

    const f32x4 zero4 = {0.f, 0.f, 0.f, 0.f};
    f32x4 acc[4][4];
#pragma unroll
    for (int i = 0; i < 4; i++)
#pragma unroll
        for (int j = 0; j < 4; j++) acc[i][j] = zero4;

    for (int k0 = 0; k0 < 512; k0 += 32) {
        __syncthreads();
#pragma unroll
        for (int i = 0; i < 2; i++) {
            const int e = t + 256 * i;
            const int r = e >> 2, c0 = (e & 3) * 8;
            *(int4*)(&As[r * 32 + c0])  = *(const int4*)(&A  [(size_t)(m0 + r) * 512 + k0 + c0]);
            *(int4*)(&Bs0[r * 32 + c0]) = *(const int4*)(&Wt0[(size_t)(n0 + r) * 512 + k0 + c0]);
            *(int4*)(&Bs1[r * 32 + c0]) = *(const int4*)(&Wt1[(size_t)(n0 + r) * 512 + k0 + c0]);
        }
        __syncthreads();

#pragma unroll
        for (int i = 0; i < 4; i++) {
            const bf16x8 a = *(const bf16x8*)(&As[(wm + i * 16 + lr) * 32 + lq * 8]);
#pragma unroll
            for (int j = 0; j < 4; j++) {
                const int bo = (wn + j * 16 + lr) * 32 + lq * 8;
                const bf16x8 b0 = *(const bf16x8*)(&Bs0[bo]);
                const bf16x8 b1 = *(const bf16x8*)(&Bs1[bo]);
                f32x4 c = acc[i][j];
                c = __builtin_amdgcn_mfma_f32_16x16x32_bf16(a, b0, c, 0, 0, 0);
                c = __builtin_amdgcn_mfma_f32_16x16x32_bf16(a, b1, c, 0, 0, 0);
                acc[i][j] = c;
            }
        }
    }

#pragma unroll
    for (int j = 0; j < 4; j++) {
        const int n = n0 + wn + j * 16 + lr;
        const float bv = bias[n];
#pragma unroll
        for (int i = 0; i < 4; i++) {
#pragma unroll
            for (int r = 0; r < 4; r++) {
                const int m = m0 + wm + i * 16 + lq * 4 + r;
                out[(size_t)m * 512 + n] = acc[i][j][r] + bv;
            }
        }
    }
}

// ---------------- launch ----------------
extern "C" void kernel_launch(void* const* d_in, const int* in_sizes, int n_in,
                              void* d_out, int out_size, void* d_ws, size_t ws_size,
                              hipStream_t stream) {
    const float* x = nullptr; const float* Wqkv = nullptr; const float* bqkv = nullptr;
    const float* Wout = nullptr; const float* bout = nullptr;
    for (int i = 0; i < n_in; i++) {
        switch (in_sizes[i]) {
            case 4194304: x    = (const float*)d_in[i]; break;
            case 786432:  Wqkv = (const float*)d_in[i]; break;
            case 1536:    bqkv = (const float*)d_in[i]; break;
            case 262144:  Wout = (const float*)d_in[i]; break;
            case 512:     bout = (const float*)d_in[i]; break;
            default: break;
        }
    }
    if (!x)    x    = (const float*)d_in[0];
    if (!Wqkv) Wqkv = (const float*)d_in[1];
    if (!bqkv) bqkv = (const float*)d_in[2];
    if (!Wout) Wout = (const float*)d_in[3];
    if (!bout) bout = (const float*)d_in[4];

    float* out = (float*)d_out;

    // Layout (48 MB ws): q 0-16 | k 16-32 | vt 32-40 | ao 40-48
    // khi (RNE bf16 K, 8 MB) lives in d_out scratch — dead until gemm_out
    // fully overwrites it at the end (stream-ordered; proven safe in R1).
    char* ws = (char*)d_ws;
    float* q_ws  = (float*)(ws);
    float* k_ws  = (float*)(ws + (16ull << 20));
    u16* vt_ws = (u16*)(ws + (32ull << 20));
    u16* ao_ws = (u16*)(ws + (40ull << 20));
    u16* khi_ws = (u16*)d_out;                             // 8 MB of the 16 MB out buf
    u16* wt0 = (u16*)(ws + (40ull << 20));                 // ao region, dead pre-attn
    u16* wt1 = (u16*)(ws + (40ull << 20) + 1572864);
    u16* wt2 = (u16*)(ws + (40ull << 20) + 3145728);
    u16* wo0 = (u16*)(ws + (32ull << 20));                 // vt region, dead post-attn
    u16* wo1 = (u16*)(ws + (32ull << 20) + 524288);

    prep_split_wT<<<3072, 256, 0, stream>>>(Wqkv, 1536, 1536 * 512, wt0, wt1, wt2);
    gemm_qkv_mfma<<<dim3(12, 64), 256, 0, stream>>>(
        x, wt0, wt1, wt2, bqkv, q_ws, k_ws, khi_ws, vt_ws);
    attn_mfma128<<<dim3(16, BHN), 512, 0, stream>>>(q_ws, k_ws, khi_ws, vt_ws, ao_ws);
    prep_split_wT<<<1024, 256, 0, stream>>>(Wout, 512, 512 * 512, wo0, wo1, nullptr);
    gemm_out_mfma<<<dim3(4, 64), 256, 0, stream>>>(ao_ws, wo0, wo1, bout, out);
}

// Round 7
// 413.730 us; speedup vs baseline: 1.2782x; 1.2782x over previous
//
#include <hip/hip_runtime.h>

// ---------------- problem constants ----------------
#define S_   2048
#define DM   512
#define HD   64
#define BHN  32

typedef unsigned short u16;
typedef __bf16 bf16x8 __attribute__((ext_vector_type(8)));
typedef float  f32x4  __attribute__((ext_vector_type(4)));

__device__ __forceinline__ float bf2f(u16 u) {
    union { unsigned int i; float f; } v; v.i = ((unsigned int)u) << 16; return v.f;
}
__device__ __forceinline__ u16 f2bf(float f) {
    union { float f; unsigned int i; } v; v.f = f;
    unsigned int i = v.i;
    return (u16)((i + 0x7FFFu + ((i >> 16) & 1u)) >> 16);   // RNE
}
// RNE 3-term split (Q only — pass B consumes fq0 alone; RNE halves its error).
__device__ __forceinline__ void split3(float x, u16& b0, u16& b1, u16& b2) {
    b0 = f2bf(x);
    const float r0 = x - bf2f(b0);
    b1 = f2bf(r0);
    const float r1 = r0 - bf2f(b1);
    b2 = f2bf(r1);
}
// Truncation 3-term split: EXACT (x == b0+b1+b2) and ~3x fewer VALU ops.
__device__ __forceinline__ void split3t(float x, u16& b0, u16& b1, u16& b2) {
    union { float f; unsigned int i; } v; v.f = x;
    const unsigned int i0 = v.i & 0xFFFF0000u;
    b0 = (u16)(i0 >> 16);
    union { float f; unsigned int i; } w0c; w0c.i = i0;
    const float r0 = x - w0c.f;
    union { float f; unsigned int i; } u; u.f = r0;
    const unsigned int i1 = u.i & 0xFFFF0000u;
    b1 = (u16)(i1 >> 16);
    union { float f; unsigned int i; } w1c; w1c.i = i1;
    const float r1 = r0 - w1c.f;
    union { float f; unsigned int i; } z; z.f = r1;
    b2 = (u16)(z.i >> 16);
}

// ---------------- prep: W[k][n] fp32 -> transposed bf16 splits [n][k] ----------------
__global__ __launch_bounds__(256) void prep_split_wT(
    const float* __restrict__ W, int N, int total,
    u16* __restrict__ w0, u16* __restrict__ w1, u16* __restrict__ w2)
{
    for (int idx = blockIdx.x * 256 + threadIdx.x; idx < total; idx += gridDim.x * 256) {
        const int n = idx >> 9, k = idx & 511;      // K = 512
        u16 a0, a1, a2;
        split3t(W[(size_t)k * N + n], a0, a1, a2);
        w0[idx] = a0; w1[idx] = a1;
        if (w2) w2[idx] = a2;
    }
}

// ---------------- QKV GEMM: MFMA, 3-split x, 3-split W^T ----------------
// K written twice: fp32 (pass-A splits + band refine) and RNE bf16 (khi,
// consumed by pass-B staging — bit-identical to the f2bf pass B used to do).
__global__ __launch_bounds__(256) void gemm_qkv_mfma(
    const float* __restrict__ A, const u16* __restrict__ Wt0, const u16* __restrict__ Wt1,
    const u16* __restrict__ Wt2, const float* __restrict__ bias,
    float* __restrict__ qh, float* __restrict__ kh, u16* __restrict__ khi,
    u16* __restrict__ vt)
{
    __shared__ __attribute__((aligned(16))) u16 As0[128 * 32], As1[128 * 32], As2[128 * 32];
    __shared__ __attribute__((aligned(16))) u16 Bs0[128 * 32], Bs1[128 * 32], Bs2[128 * 32];

    const int t  = threadIdx.x;
    const int m0 = blockIdx.y * 128, n0 = blockIdx.x * 128;
    const int w  = t >> 6, l = t & 63;
    const int wm = (w >> 1) * 64, wn = (w & 1) * 64;
    const int lr = l & 15, lq = l >> 4;

    const f32x4 zero4 = {0.f, 0.f, 0.f, 0.f};
    f32x4 acc[4][4];
#pragma unroll
    for (int i = 0; i < 4; i++)
#pragma unroll
        for (int j = 0; j < 4; j++) acc[i][j] = zero4;

    for (int k0 = 0; k0 < 512; k0 += 32) {
        __syncthreads();
#pragma unroll
        for (int i = 0; i < 4; i++) {
            const int e = t + 256 * i;
            const int r = e >> 3, c4 = (e & 7) * 4;
            const float4 f = *(const float4*)(&A[(size_t)(m0 + r) * 512 + k0 + c4]);
            const float xv[4] = {f.x, f.y, f.z, f.w};
            u16 a0[4], a1[4], a2[4];
#pragma unroll
            for (int j = 0; j < 4; j++) split3t(xv[j], a0[j], a1[j], a2[j]);
            int2 p0, p1, p2;
            p0.x = a0[0] | (a0[1] << 16); p0.y = a0[2] | (a0[3] << 16);
            p1.x = a1[0] | (a1[1] << 16); p1.y = a1[2] | (a1[3] << 16);
            p2.x = a2[0] | (a2[1] << 16); p2.y = a2[2] | (a2[3] << 16);
            *(int2*)(&As0[r * 32 + c4]) = p0;
            *(int2*)(&As1[r * 32 + c4]) = p1;
            *(int2*)(&As2[r * 32 + c4]) = p2;
        }
#pragma unroll
        for (int i = 0; i < 2; i++) {
            const int e = t + 256 * i;
            const int r = e >> 2, c0 = (e & 3) * 8;
            *(int4*)(&Bs0[r * 32 + c0]) = *(const int4*)(&Wt0[(size_t)(n0 + r) * 512 + k0 + c0]);
            *(int4*)(&Bs1[r * 32 + c0]) = *(const int4*)(&Wt1[(size_t)(n0 + r) * 512 + k0 + c0]);
            *(int4*)(&Bs2[r * 32 + c0]) = *(const int4*)(&Wt2[(size_t)(n0 + r) * 512 + k0 + c0]);
        }
        __syncthreads();

#pragma unroll
        for (int i = 0; i < 4; i++) {
            const int ao = (wm + i * 16 + lr) * 32 + lq * 8;
            const bf16x8 a0 = *(const bf16x8*)(&As0[ao]);
            const bf16x8 a1 = *(const bf16x8*)(&As1[ao]);
            const bf16x8 a2 = *(const bf16x8*)(&As2[ao]);
#pragma unroll
            for (int j = 0; j < 4; j++) {
                const int bo = (wn + j * 16 + lr) * 32 + lq * 8;
                const bf16x8 b0 = *(const bf16x8*)(&Bs0[bo]);
                const bf16x8 b1 = *(const bf16x8*)(&Bs1[bo]);
                const bf16x8 b2 = *(const bf16x8*)(&Bs2[bo]);
                f32x4 c = acc[i][j];
                c = __builtin_amdgcn_mfma_f32_16x16x32_bf16(a0, b0, c, 0, 0, 0);
                c = __builtin_amdgcn_mfma_f32_16x16x32_bf16(a0, b1, c, 0, 0, 0);
                c = __builtin_amdgcn_mfma_f32_16x16x32_bf16(a1, b0, c, 0, 0, 0);
                c = __builtin_amdgcn_mfma_f32_16x16x32_bf16(a1, b1, c, 0, 0, 0);
                c = __builtin_amdgcn_mfma_f32_16x16x32_bf16(a0, b2, c, 0, 0, 0);
                c = __builtin_amdgcn_mfma_f32_16x16x32_bf16(a2, b0, c, 0, 0, 0);
                acc[i][j] = c;
            }
        }
    }

#pragma unroll
    for (int j = 0; j < 4; j++) {
        const int n = n0 + wn + j * 16 + lr;
        const float bv = bias[n];
        const int part = n >> 9, within = n & 511;
        const int h = within >> 6, d = within & 63;
#pragma unroll
        for (int i = 0; i < 4; i++) {
#pragma unroll
            for (int r = 0; r < 4; r++) {
                const int m = m0 + wm + i * 16 + lq * 4 + r;
                const int b = m >> 11, ns = m & 2047;
                const float val = acc[i][j][r] + bv;
                if (part == 0) {
                    qh[(((size_t)(b * 8 + h)) * S_ + ns) * HD + d] = val;
                } else if (part == 1) {
                    const size_t kidx = (((size_t)(b * 8 + h)) * S_ + ns) * HD + d;
                    kh[kidx]  = val;
                    khi[kidx] = f2bf(val);
                } else {
                    vt[(((size_t)(b * 8 + h)) * HD + d) * S_ + ns] = f2bf(val);
                }
            }
        }
    }
}

// ---------------- attention: 128 q-rows/block, 8 waves, double-buffered LDS ----------------
// Pipeline shape fixed per R2/R6 lesson (hipcc drains vmcnt(0) at every barrier):
//   load(jt+1) -> compute from buf[cur] -> ds_write buf[cur^1] -> barrier.
// Loads are issued and CONSUMED within the same inter-barrier region, so the
// barrier drain costs nothing and HBM/L2 latency hides under compute.
// Pass A: 1 barrier/jt (was 2). Pass B: 2 barriers/jt, staging overlapped.
// LDS union: lds[2][3][64*LDH] = 55.3 KB (same footprint as before; 2 blocks/CU).
// Pass-B aliasing: K-hi = lds[cur][0], V = lds[cur][1], Ps = lds[0..1][2].
#define LDH 72

__global__ __launch_bounds__(512) void attn_mfma128(
    const float* __restrict__ q_ws, const float* __restrict__ k_ws,
    const u16* __restrict__ khi_ws, const u16* __restrict__ vt_ws,
    u16* __restrict__ ao_ws)
{
    __shared__ __attribute__((aligned(16))) u16 lds[2][3][64 * LDH];
    __shared__ float smaxL[8][32];

    const int t  = threadIdx.x;
    const int w  = t >> 6, l = t & 63;
    const int lr = l & 15, lq = l >> 4;
    const int bh = blockIdx.y, b = bh >> 3, h = bh & 7;
    const int q0 = blockIdx.x * 128;

    const float* qg  = q_ws + ((size_t)bh * S_ + q0) * HD;
    const float* kg0 = k_ws + (size_t)bh * S_ * HD;
    const u16*   kh0 = khi_ws + (size_t)bh * S_ * HD;
    const u16*   vb  = vt_ws + (size_t)bh * HD * S_;

    // ---- stage Q 3-split (scale folded) in two 64-row halves through lds[0] ----
    bf16x8 fq0[2], fq1[2], fq2[2];    // [kc]
#pragma unroll
    for (int h2 = 0; h2 < 2; h2++) {
        __syncthreads();
#pragma unroll
        for (int i = 0; i < 2; i++) {
            const int e = t + 512 * i;                 // 1024 float4s over 64x64
            const int row = e >> 4, c0 = (e & 15) * 4;
            const float4 f = *(const float4*)(qg + (size_t)h2 * 4096 + (size_t)e * 4);
            const float xv[4] = {f.x * 0.125f, f.y * 0.125f, f.z * 0.125f, f.w * 0.125f};
            u16 a0[4], a1[4], a2[4];
#pragma unroll
            for (int j = 0; j < 4; j++) split3(xv[j], a0[j], a1[j], a2[j]);
            int2 p0, p1, p2;
            p0.x = a0[0] | (a0[1] << 16); p0.y = a0[2] | (a0[3] << 16);
            p1.x = a1[0] | (a1[1] << 16); p1.y = a1[2] | (a1[3] << 16);
            p2.x = a2[0] | (a2[1] << 16); p2.y = a2[2] | (a2[3] << 16);
            *(int2*)(&lds[0][0][row * LDH + c0]) = p0;
            *(int2*)(&lds[0][1][row * LDH + c0]) = p1;
            *(int2*)(&lds[0][2][row * LDH + c0]) = p2;
        }
        __syncthreads();
        if ((w >> 2) == h2) {
#pragma unroll
            for (int kc = 0; kc < 2; kc++) {
                const int o = ((w & 3) * 16 + lr) * LDH + kc * 32 + lq * 8;
                fq0[kc] = *(const bf16x8*)(&lds[0][0][o]);
                fq1[kc] = *(const bf16x8*)(&lds[0][1][o]);
                fq2[kc] = *(const bf16x8*)(&lds[0][2][o]);
            }
        }
    }

    const f32x4 zero4 = {0.f, 0.f, 0.f, 0.f};
    double lsum[4];
#pragma unroll
    for (int r = 0; r < 4; r++) lsum[r] = 0.0;

    // ---- pass A: denominator; dbuf pipeline, 1 barrier/jt ----
    int cur = 0;
    {   // prologue: stage tile 0 into lds[0]
        float4 ka0[2];
#pragma unroll
        for (int i = 0; i < 2; i++)
            ka0[i] = *(const float4*)(kg0 + (size_t)(t + 512 * i) * 4);
        __syncthreads();                    // Q-frag reads of lds[0] complete
#pragma unroll
        for (int i = 0; i < 2; i++) {
            const int e = t + 512 * i;
            const int row = e >> 4, c0 = (e & 15) * 4;
            const float4 f = ka0[i];
            const float xv[4] = {f.x, f.y, f.z, f.w};
            u16 a0[4], a1[4], a2[4];
#pragma unroll
            for (int j = 0; j < 4; j++) split3t(xv[j], a0[j], a1[j], a2[j]);
            int2 p0, p1, p2;
            p0.x = a0[0] | (a0[1] << 16); p0.y = a0[2] | (a0[3] << 16);
            p1.x = a1[0] | (a1[1] << 16); p1.y = a1[2] | (a1[3] << 16);
            p2.x = a2[0] | (a2[1] << 16); p2.y = a2[2] | (a2[3] << 16);
            *(int2*)(&lds[0][0][row * LDH + c0]) = p0;
            *(int2*)(&lds[0][1][row * LDH + c0]) = p1;
            *(int2*)(&lds[0][2][row * LDH + c0]) = p2;
        }
        __syncthreads();
    }

    for (int jt = 0; jt < 32; jt++) {
        // issue next tile's loads — consumed by the ds_write BELOW (same
        // inter-barrier region), latency hides under the MFMA+exp block.
        const int jn = (jt + 1 < 32) ? jt + 1 : 31;
        float4 ka[2];
#pragma unroll
        for (int i = 0; i < 2; i++)
            ka[i] = *(const float4*)(kg0 + (size_t)jn * 64 * HD + (size_t)(t + 512 * i) * 4);

        // compute from buf[cur]
        const u16* K0c = lds[cur][0];
        const u16* K1c = lds[cur][1];
        const u16* K2c = lds[cur][2];
        float tmax = -1e30f;
#pragma unroll
        for (int nt = 0; nt < 4; nt++) {
            f32x4 aHH = zero4, aC = zero4;
#pragma unroll
            for (int kc = 0; kc < 2; kc++) {
                const int ko = (nt * 16 + lr) * LDH + kc * 32 + lq * 8;
                const bf16x8 k0 = *(const bf16x8*)(&K0c[ko]);
                const bf16x8 k1 = *(const bf16x8*)(&K1c[ko]);
                const bf16x8 k2 = *(const bf16x8*)(&K2c[ko]);
                aHH = __builtin_amdgcn_mfma_f32_16x16x32_bf16(fq0[kc], k0, aHH, 0, 0, 0);
                aC  = __builtin_amdgcn_mfma_f32_16x16x32_bf16(fq0[kc], k1, aC, 0, 0, 0);
                aC  = __builtin_amdgcn_mfma_f32_16x16x32_bf16(fq1[kc], k0, aC, 0, 0, 0);
                aC  = __builtin_amdgcn_mfma_f32_16x16x32_bf16(fq1[kc], k1, aC, 0, 0, 0);
                aC  = __builtin_amdgcn_mfma_f32_16x16x32_bf16(fq0[kc], k2, aC, 0, 0, 0);
                aC  = __builtin_amdgcn_mfma_f32_16x16x32_bf16(fq2[kc], k0, aC, 0, 0, 0);
            }
#pragma unroll
            for (int r = 0; r < 4; r++) {
                const float s = fminf(fmaxf(aHH[r] + aC[r], -30.f), 30.f);
                tmax = fmaxf(tmax, s);
                lsum[r] += (double)__expf(s);
            }
        }
        // wave-tile max of ACCURATE scores (read by same wave in pass B)
#pragma unroll
        for (int off = 1; off < 64; off <<= 1)
            tmax = fmaxf(tmax, __shfl_xor(tmax, off, 64));
        if (l == 0) smaxL[w][jt] = tmax;

        // stage next tile into buf[cur^1] (disjoint from all buf[cur] readers)
        u16* K0n = lds[cur ^ 1][0];
        u16* K1n = lds[cur ^ 1][1];
        u16* K2n = lds[cur ^ 1][2];
#pragma unroll
        for (int i = 0; i < 2; i++) {
            const int e = t + 512 * i;
            const int row = e >> 4, c0 = (e & 15) * 4;
            const float4 f = ka[i];
            const float xv[4] = {f.x, f.y, f.z, f.w};
            u16 a0[4], a1[4], a2[4];
#pragma unroll
            for (int j = 0; j < 4; j++) split3t(xv[j], a0[j], a1[j], a2[j]);
            int2 p0, p1, p2;
            p0.x = a0[0] | (a0[1] << 16); p0.y = a0[2] | (a0[3] << 16);
            p1.x = a1[0] | (a1[1] << 16); p1.y = a1[2] | (a1[3] << 16);
            p2.x = a2[0] | (a2[1] << 16); p2.y = a2[2] | (a2[3] << 16);
            *(int2*)(&K0n[row * LDH + c0]) = p0;
            *(int2*)(&K1n[row * LDH + c0]) = p1;
            *(int2*)(&K2n[row * LDH + c0]) = p2;
        }
        __syncthreads();   // publishes buf[cur^1]; all buf[cur] reads already done
        cur ^= 1;
    }

#pragma unroll
    for (int r = 0; r < 4; r++) {
#pragma unroll
        for (int off = 1; off < 16; off <<= 1)
            lsum[r] += __shfl_xor(lsum[r], off, 64);
    }
    double l_d[4]; float inv_l[4];
#pragma unroll
    for (int r = 0; r < 4; r++) {
        l_d[r] = lsum[r];
        inv_l[r] = (float)(1.0 / lsum[r]);
    }

    // skip threshold: tile all-zero iff smax < ln(0.0085 * min-row-Z)
    float zmin4 = (float)fmin(fmin(lsum[0], lsum[1]), fmin(lsum[2], lsum[3]));
    zmin4 = fminf(zmin4, __shfl_xor(zmin4, 16, 64));
    zmin4 = fminf(zmin4, __shfl_xor(zmin4, 32, 64));
    const float sthr = logf(0.0085f * zmin4);

    f32x4 oacc[4];
#pragma unroll
    for (int dt = 0; dt < 4; dt++) oacc[dt] = zero4;

    // ---- pass B: dbuf pipeline; K-hi = lds[cur][0], V = lds[cur][1], Ps = lds[*][2] ----
    u16* const Pw = &lds[w >> 2][2][(w & 3) * 16 * LDH];

    {   // prologue: stage tile 0 (pass-A reads all completed before its last barrier)
        const int row = t >> 3, c0 = (t & 7) * 8;
        const int4 kb0 = *(const int4*)(&kh0[(size_t)row * HD + c0]);
        const int4 vr0 = *(const int4*)(&vb[(size_t)row * S_ + c0]);
        *(int4*)(&lds[0][0][row * LDH + c0]) = kb0;
        *(int4*)(&lds[0][1][row * LDH + c0]) = vr0;
        __syncthreads();
    }
    cur = 0;

    for (int jt = 0; jt < 32; jt++) {
        // issue next tile's loads — consumed by ds_write below, before barrier 1
        const int jn = (jt + 1 < 32) ? jt + 1 : 31;
        const int srow = t >> 3, sc0 = (t & 7) * 8;
        const int4 kb = *(const int4*)(&kh0[(size_t)jn * 64 * HD + (size_t)srow * HD + sc0]);
        const int4 vr = *(const int4*)(&vb[(size_t)srow * S_ + jn * 64 + sc0]);

        const bool live = (smaxL[w][jt] >= sthr);   // wave-uniform branch

        if (live) {
            const u16* Kc = lds[cur][0];
#pragma unroll
            for (int nt = 0; nt < 4; nt++) {
                f32x4 sacc = zero4;
#pragma unroll
                for (int kc = 0; kc < 2; kc++) {
                    const bf16x8 k0 = *(const bf16x8*)(&Kc[(nt * 16 + lr) * LDH + kc * 32 + lq * 8]);
                    sacc = __builtin_amdgcn_mfma_f32_16x16x32_bf16(fq0[kc], k0, sacc, 0, 0, 0);
                }
#pragma unroll
                for (int r = 0; r < 4; r++) {
                    const float s = fminf(fmaxf(sacc[r], -30.f), 30.f);
                    const float p = __expf(s) * inv_l[r];
                    u16 pb;
                    if (p > 0.0115f) {
                        pb = f2bf(p);
                    } else if (p < 0.009f) {
                        pb = 0;
                    } else {
                        const int row = q0 + w * 16 + lq * 4 + r;
                        const int col = jt * 64 + nt * 16 + lr;
                        const float* qr  = q_ws + ((size_t)bh * S_ + row) * HD;
                        const float* kcv = k_ws + ((size_t)bh * S_ + col) * HD;
                        double s64 = 0.0;
                        for (int d = 0; d < HD; d++) s64 += (double)qr[d] * (double)kcv[d];
                        s64 = fmin(fmax(s64 * 0.125, -30.0), 30.0);
                        const double pd = exp(s64) / l_d[r];
                        pb = (pd > 0.01) ? f2bf((float)pd) : (u16)0;
                    }
                    Pw[(lq * 4 + r) * LDH + nt * 16 + lr] = pb;
                }
            }
        }
        // stage next tile into buf[cur^1] (disjoint from score reads of buf[cur])
        *(int4*)(&lds[cur ^ 1][0][srow * LDH + sc0]) = kb;
        *(int4*)(&lds[cur ^ 1][1][srow * LDH + sc0]) = vr;
        __syncthreads();   // Ps fence + publishes staged tile
        if (live) {
            const u16* Vc = lds[cur][1];
#pragma unroll
            for (int kc = 0; kc < 2; kc++) {
                const bf16x8 ap = *(const bf16x8*)(&Pw[lr * LDH + kc * 32 + lq * 8]);
#pragma unroll
                for (int dt = 0; dt < 4; dt++) {
                    const bf16x8 bv = *(const bf16x8*)(&Vc[(dt * 16 + lr) * LDH + kc * 32 + lq * 8]);
                    oacc[dt] = __builtin_amdgcn_mfma_f32_16x16x32_bf16(ap, bv, oacc[dt], 0, 0, 0);
                }
            }
        }
        __syncthreads();   // PV reads of buf[cur] / Ps done before next overwrite
        cur ^= 1;
    }

    // epilogue
#pragma unroll
    for (int dt = 0; dt < 4; dt++) {
#pragma unroll
        for (int r = 0; r < 4; r++) {
            const int row = q0 + w * 16 + lq * 4 + r;
            const int d   = dt * 16 + lr;
            ao_ws[((size_t)b * S_ + row) * DM + h * HD + d] = f2bf(oacc[dt][r]);
        }
    }
}

// ---------------- out projection: MFMA, bf16 A x 2-split W^T -> fp32 out ----------------
__global__ __launch_bounds__(256) void gemm_out_mfma(
    const u16* __restrict__ A, const u16* __restrict__ Wt0, const u16* __restrict__ Wt1,
    const float* __restrict__ bias, float* __restrict__ out)
{
    __shared__ __attribute__((aligned(16))) u16 As[128 * 32];
    __shared__ __attribute__((aligned(16))) u16 Bs0[128 * 32], Bs1[128 * 32];

    const int t  = threadIdx.x;
    const int m0 = blockIdx.y * 128, n0 = blockIdx.x * 128;
    const int w  = t >> 6, l = t & 63;
    const int wm = (w >> 1) * 64, wn = (w & 1) * 64;
    const int lr = l & 15, lq = l >> 4;

    const f32x4 zero4 = {0.f, 0.f, 0.f, 0.f};
    f32x4 acc[4][4];
#pragma unroll
    for (int i = 0; i < 4; i++)
#pragma unroll
        for (int j = 0; j < 4; j++) acc[i][j] = zero4;

    for (int k0 = 0; k0 < 512; k0 += 32) {
        __syncthreads();
#pragma unroll
        for (int i = 0; i < 2; i++) {
            const int e = t + 256 * i;
            const int r = e >> 2, c0 = (e & 3) * 8;
            *(int4*)(&As[r * 32 + c0])  = *(const int4*)(&A  [(size_t)(m0 + r) * 512 + k0 + c0]);
            *(int4*)(&Bs0[r * 32 + c0]) = *(const int4*)(&Wt0[(size_t)(n0 + r) * 512 + k0 + c0]);
            *(int4*)(&Bs1[r * 32 + c0]) = *(const int4*)(&Wt1[(size_t)(n0 + r) * 512 + k0 + c0]);
        }
        __syncthreads();

#pragma unroll
        for (int i = 0; i < 4; i++) {
            const bf16x8 a = *(const bf16x8*)(&As[(wm + i * 16 + lr) * 32 + lq * 8]);
#pragma unroll
            for (int j = 0; j < 4; j++) {
                const int bo = (wn + j * 16 + lr) * 32 + lq * 8;
                const bf16x8 b0 = *(const bf16x8*)(&Bs0[bo]);
                const bf16x8 b1 = *(const bf16x8*)(&Bs1[bo]);
                f32x4 c = acc[i][j];
                c = __builtin_amdgcn_mfma_f32_16x16x32_bf16(a, b0, c, 0, 0, 0);
                c = __builtin_amdgcn_mfma_f32_16x16x32_bf16(a, b1, c, 0, 0, 0);
                acc[i][j] = c;
            }
        }
    }

#pragma unroll
    for (int j = 0; j < 4; j++) {
        const int n = n0 + wn + j * 16 + lr;
        const float bv = bias[n];
#pragma unroll
        for (int i = 0; i < 4; i++) {
#pragma unroll
            for (int r = 0; r < 4; r++) {
                const int m = m0 + wm + i * 16 + lq * 4 + r;
                out[(size_t)m * 512 + n] = acc[i][j][r] + bv;
            }
        }
    }
}

// ---------------- launch ----------------
extern "C" void kernel_launch(void* const* d_in, const int* in_sizes, int n_in,
                              void* d_out, int out_size, void* d_ws, size_t ws_size,
                              hipStream_t stream) {
    const float* x = nullptr; const float* Wqkv = nullptr; const float* bqkv = nullptr;
    const float* Wout = nullptr; const float* bout = nullptr;
    for (int i = 0; i < n_in; i++) {
        switch (in_sizes[i]) {
            case 4194304: x    = (const float*)d_in[i]; break;
            case 786432:  Wqkv = (const float*)d_in[i]; break;
            case 1536:    bqkv = (const float*)d_in[i]; break;
            case 262144:  Wout = (const float*)d_in[i]; break;
            case 512:     bout = (const float*)d_in[i]; break;
            default: break;
        }
    }
    if (!x)    x    = (const float*)d_in[0];
    if (!Wqkv) Wqkv = (const float*)d_in[1];
    if (!bqkv) bqkv = (const float*)d_in[2];
    if (!Wout) Wout = (const float*)d_in[3];
    if (!bout) bout = (const float*)d_in[4];

    float* out = (float*)d_out;

    // Layout (48 MB ws): q 0-16 | k 16-32 | vt 32-40 | ao 40-48
    // khi (RNE bf16 K, 8 MB) lives in d_out scratch — dead until gemm_out
    // fully overwrites it at the end (stream-ordered).
    char* ws = (char*)d_ws;
    float* q_ws  = (float*)(ws);
    float* k_ws  = (float*)(ws + (16ull << 20));
    u16* vt_ws = (u16*)(ws + (32ull << 20));
    u16* ao_ws = (u16*)(ws + (40ull << 20));
    u16* khi_ws = (u16*)d_out;                             // 8 MB of the 16 MB out buf
    u16* wt0 = (u16*)(ws + (40ull << 20));                 // ao region, dead pre-attn
    u16* wt1 = (u16*)(ws + (40ull << 20) + 1572864);
    u16* wt2 = (u16*)(ws + (40ull << 20) + 3145728);
    u16* wo0 = (u16*)(ws + (32ull << 20));                 // vt region, dead post-attn
    u16* wo1 = (u16*)(ws + (32ull << 20) + 524288);

    prep_split_wT<<<3072, 256, 0, stream>>>(Wqkv, 1536, 1536 * 512, wt0, wt1, wt2);
    gemm_qkv_mfma<<<dim3(12, 64), 256, 0, stream>>>(
        x, wt0, wt1, wt2, bqkv, q_ws, k_ws, khi_ws, vt_ws);
    attn_mfma128<<<dim3(16, BHN), 512, 0, stream>>>(q_ws, k_ws, khi_ws, vt_ws, ao_ws);
    prep_split_wT<<<1024, 256, 0, stream>>>(Wout, 512, 512 * 512, wo0, wo1, nullptr);
    gemm_out_mfma<<<dim3(4, 64), 256, 0, stream>>>(ao_ws, wo0, wo1, bout, out);
}

// Round 8
// 409.956 us; speedup vs baseline: 1.2900x; 1.0092x over previous
//
#include <hip/hip_runtime.h>

// ---------------- problem constants ----------------
#define S_   2048
#define DM   512
#define HD   64
#define BHN  32

typedef unsigned short u16;
typedef __bf16 bf16x8 __attribute__((ext_vector_type(8)));
typedef float  f32x4  __attribute__((ext_vector_type(4)));

__device__ __forceinline__ float bf2f(u16 u) {
    union { unsigned int i; float f; } v; v.i = ((unsigned int)u) << 16; return v.f;
}
__device__ __forceinline__ u16 f2bf(float f) {
    union { float f; unsigned int i; } v; v.f = f;
    unsigned int i = v.i;
    return (u16)((i + 0x7FFFu + ((i >> 16) & 1u)) >> 16);   // RNE
}
// RNE 3-term split (Q only — pass B consumes fq0 alone; RNE halves its error).
__device__ __forceinline__ void split3(float x, u16& b0, u16& b1, u16& b2) {
    b0 = f2bf(x);
    const float r0 = x - bf2f(b0);
    b1 = f2bf(r0);
    const float r1 = r0 - bf2f(b1);
    b2 = f2bf(r1);
}
// Truncation 3-term split: EXACT (x == b0+b1+b2) and ~3x fewer VALU ops.
__device__ __forceinline__ void split3t(float x, u16& b0, u16& b1, u16& b2) {
    union { float f; unsigned int i; } v; v.f = x;
    const unsigned int i0 = v.i & 0xFFFF0000u;
    b0 = (u16)(i0 >> 16);
    union { float f; unsigned int i; } w0c; w0c.i = i0;
    const float r0 = x - w0c.f;
    union { float f; unsigned int i; } u; u.f = r0;
    const unsigned int i1 = u.i & 0xFFFF0000u;
    b1 = (u16)(i1 >> 16);
    union { float f; unsigned int i; } w1c; w1c.i = i1;
    const float r1 = r0 - w1c.f;
    union { float f; unsigned int i; } z; z.f = r1;
    b2 = (u16)(z.i >> 16);
}

// ---------------- prep: W[k][n] fp32 -> transposed bf16 splits [n][k] ----------------
__global__ __launch_bounds__(256) void prep_split_wT(
    const float* __restrict__ W, int N, int total,
    u16* __restrict__ w0, u16* __restrict__ w1, u16* __restrict__ w2)
{
    for (int idx = blockIdx.x * 256 + threadIdx.x; idx < total; idx += gridDim.x * 256) {
        const int n = idx >> 9, k = idx & 511;      // K = 512
        u16 a0, a1, a2;
        split3t(W[(size_t)k * N + n], a0, a1, a2);
        w0[idx] = a0; w1[idx] = a1;
        if (w2) w2[idx] = a2;
    }
}

// ---------------- QKV GEMM: MFMA, 3-split x, 3-split W^T ----------------
// K written twice: fp32 (pass-A splits + band refine) and RNE bf16 (khi,
// consumed by pass-B staging — bit-identical to the f2bf pass B used to do).
__global__ __launch_bounds__(256) void gemm_qkv_mfma(
    const float* __restrict__ A, const u16* __restrict__ Wt0, const u16* __restrict__ Wt1,
    const u16* __restrict__ Wt2, const float* __restrict__ bias,
    float* __restrict__ qh, float* __restrict__ kh, u16* __restrict__ khi,
    u16* __restrict__ vt)
{
    __shared__ __attribute__((aligned(16))) u16 As0[128 * 32], As1[128 * 32], As2[128 * 32];
    __shared__ __attribute__((aligned(16))) u16 Bs0[128 * 32], Bs1[128 * 32], Bs2[128 * 32];

    const int t  = threadIdx.x;
    const int m0 = blockIdx.y * 128, n0 = blockIdx.x * 128;
    const int w  = t >> 6, l = t & 63;
    const int wm = (w >> 1) * 64, wn = (w & 1) * 64;
    const int lr = l & 15, lq = l >> 4;

    const f32x4 zero4 = {0.f, 0.f, 0.f, 0.f};
    f32x4 acc[4][4];
#pragma unroll
    for (int i = 0; i < 4; i++)
#pragma unroll
        for (int j = 0; j < 4; j++) acc[i][j] = zero4;

    for (int k0 = 0; k0 < 512; k0 += 32) {
        __syncthreads();
#pragma unroll
        for (int i = 0; i < 4; i++) {
            const int e = t + 256 * i;
            const int r = e >> 3, c4 = (e & 7) * 4;
            const float4 f = *(const float4*)(&A[(size_t)(m0 + r) * 512 + k0 + c4]);
            const float xv[4] = {f.x, f.y, f.z, f.w};
            u16 a0[4], a1[4], a2[4];
#pragma unroll
            for (int j = 0; j < 4; j++) split3t(xv[j], a0[j], a1[j], a2[j]);
            int2 p0, p1, p2;
            p0.x = a0[0] | (a0[1] << 16); p0.y = a0[2] | (a0[3] << 16);
            p1.x = a1[0] | (a1[1] << 16); p1.y = a1[2] | (a1[3] << 16);
            p2.x = a2[0] | (a2[1] << 16); p2.y = a2[2] | (a2[3] << 16);
            *(int2*)(&As0[r * 32 + c4]) = p0;
            *(int2*)(&As1[r * 32 + c4]) = p1;
            *(int2*)(&As2[r * 32 + c4]) = p2;
        }
#pragma unroll
        for (int i = 0; i < 2; i++) {
            const int e = t + 256 * i;
            const int r = e >> 2, c0 = (e & 3) * 8;
            *(int4*)(&Bs0[r * 32 + c0]) = *(const int4*)(&Wt0[(size_t)(n0 + r) * 512 + k0 + c0]);
            *(int4*)(&Bs1[r * 32 + c0]) = *(const int4*)(&Wt1[(size_t)(n0 + r) * 512 + k0 + c0]);
            *(int4*)(&Bs2[r * 32 + c0]) = *(const int4*)(&Wt2[(size_t)(n0 + r) * 512 + k0 + c0]);
        }
        __syncthreads();

#pragma unroll
        for (int i = 0; i < 4; i++) {
            const int ao = (wm + i * 16 + lr) * 32 + lq * 8;
            const bf16x8 a0 = *(const bf16x8*)(&As0[ao]);
            const bf16x8 a1 = *(const bf16x8*)(&As1[ao]);
            const bf16x8 a2 = *(const bf16x8*)(&As2[ao]);
#pragma unroll
            for (int j = 0; j < 4; j++) {
                const int bo = (wn + j * 16 + lr) * 32 + lq * 8;
                const bf16x8 b0 = *(const bf16x8*)(&Bs0[bo]);
                const bf16x8 b1 = *(const bf16x8*)(&Bs1[bo]);
                const bf16x8 b2 = *(const bf16x8*)(&Bs2[bo]);
                f32x4 c = acc[i][j];
                c = __builtin_amdgcn_mfma_f32_16x16x32_bf16(a0, b0, c, 0, 0, 0);
                c = __builtin_amdgcn_mfma_f32_16x16x32_bf16(a0, b1, c, 0, 0, 0);
                c = __builtin_amdgcn_mfma_f32_16x16x32_bf16(a1, b0, c, 0, 0, 0);
                c = __builtin_amdgcn_mfma_f32_16x16x32_bf16(a1, b1, c, 0, 0, 0);
                c = __builtin_amdgcn_mfma_f32_16x16x32_bf16(a0, b2, c, 0, 0, 0);
                c = __builtin_amdgcn_mfma_f32_16x16x32_bf16(a2, b0, c, 0, 0, 0);
                acc[i][j] = c;
            }
        }
    }

#pragma unroll
    for (int j = 0; j < 4; j++) {
        const int n = n0 + wn + j * 16 + lr;
        const float bv = bias[n];
        const int part = n >> 9, within = n & 511;
        const int h = within >> 6, d = within & 63;
#pragma unroll
        for (int i = 0; i < 4; i++) {
#pragma unroll
            for (int r = 0; r < 4; r++) {
                const int m = m0 + wm + i * 16 + lq * 4 + r;
                const int b = m >> 11, ns = m & 2047;
                const float val = acc[i][j][r] + bv;
                if (part == 0) {
                    qh[(((size_t)(b * 8 + h)) * S_ + ns) * HD + d] = val;
                } else if (part == 1) {
                    const size_t kidx = (((size_t)(b * 8 + h)) * S_ + ns) * HD + d;
                    kh[kidx]  = val;
                    khi[kidx] = f2bf(val);
                } else {
                    vt[(((size_t)(b * 8 + h)) * HD + d) * S_ + ns] = f2bf(val);
                }
            }
        }
    }
}

// ---------------- attention: 128 q-rows/block, 8 waves, fragment-linear LDS ----------------
// R7 pipeline (issue-early/consume-before-barrier, dbuf) + fragment-linear tiles:
// every 64x64 tile is stored as MFMA fragments, chunk ((nt*2+kc)*64 + lane)*8 u16.
// All compute ds_read_b128 are then base + l*16B (contiguous 1KB per wave-read,
// conflict-free); the old (row*LDH) pattern was an 8-way bank conflict
// (1.85e7 conflict cycles ~ 12%+ of kernel time). Staging threads each produce
// whole chunks so writes stay linear. lsum accumulation moved f64 -> f32
// (128 sequential adds, ~1e-6 rel error; l_d = (double)cast for refine).
// LDS: pool[2][3][4096] u16 = 48KB + smax 1KB. Pass-B: K-hi=pool[cur][0],
// V=pool[cur][1], P(frag-linear, 1KB/wave)=pool[0..1][2].
__global__ __launch_bounds__(512) void attn_mfma128(
    const float* __restrict__ q_ws, const float* __restrict__ k_ws,
    const u16* __restrict__ khi_ws, const u16* __restrict__ vt_ws,
    u16* __restrict__ ao_ws)
{
    __shared__ __attribute__((aligned(16))) u16 pool[2][3][4096];
    __shared__ float smaxL[8][32];

    const int t  = threadIdx.x;
    const int w  = t >> 6, l = t & 63;
    const int lr = l & 15, lq = l >> 4;
    const int bh = blockIdx.y, b = bh >> 3, h = bh & 7;
    const int q0 = blockIdx.x * 128;

    const float* qg  = q_ws + ((size_t)bh * S_ + q0) * HD;
    const float* kg0 = k_ws + (size_t)bh * S_ * HD;
    const u16*   kh0 = khi_ws + (size_t)bh * S_ * HD;
    const u16*   vb  = vt_ws + (size_t)bh * HD * S_;

    // staging coords: thread t produces fragment-chunk t of a 64x64 tile.
    // chunk t: tile row sr, col base sd (8 elements); LDS dst = t*8 (linear!).
    const int cw = t >> 6, cl = t & 63;
    const int sr = ((cw >> 1) << 4) | (cl & 15);
    const int sd = ((cw & 1) << 5) | (((cl >> 4) & 3) << 3);
    const int sdst = t * 8;

    // ---- stage Q 3-split (scale folded) in two 64-row halves through pool[0] ----
    bf16x8 fq0[2], fq1[2], fq2[2];    // [kc]
#pragma unroll
    for (int h2 = 0; h2 < 2; h2++) {
        __syncthreads();
        {
            const float* src = qg + (size_t)h2 * 4096 + sr * 64 + sd;
            const float4 fA = *(const float4*)(src);
            const float4 fB = *(const float4*)(src + 4);
            const float xv[8] = {fA.x * 0.125f, fA.y * 0.125f, fA.z * 0.125f, fA.w * 0.125f,
                                 fB.x * 0.125f, fB.y * 0.125f, fB.z * 0.125f, fB.w * 0.125f};
            u16 a0[8], a1[8], a2[8];
#pragma unroll
            for (int j = 0; j < 8; j++) split3(xv[j], a0[j], a1[j], a2[j]);
            int4 p0, p1, p2;
            p0.x = a0[0] | (a0[1] << 16); p0.y = a0[2] | (a0[3] << 16);
            p0.z = a0[4] | (a0[5] << 16); p0.w = a0[6] | (a0[7] << 16);
            p1.x = a1[0] | (a1[1] << 16); p1.y = a1[2] | (a1[3] << 16);
            p1.z = a1[4] | (a1[5] << 16); p1.w = a1[6] | (a1[7] << 16);
            p2.x = a2[0] | (a2[1] << 16); p2.y = a2[2] | (a2[3] << 16);
            p2.z = a2[4] | (a2[5] << 16); p2.w = a2[6] | (a2[7] << 16);
            *(int4*)(&pool[0][0][sdst]) = p0;
            *(int4*)(&pool[0][1][sdst]) = p1;
            *(int4*)(&pool[0][2][sdst]) = p2;
        }
        __syncthreads();
        if ((w >> 2) == h2) {
#pragma unroll
            for (int kc = 0; kc < 2; kc++) {
                const int o = ((((w & 3) << 1) + kc) << 9) + l * 8;
                fq0[kc] = *(const bf16x8*)(&pool[0][0][o]);
                fq1[kc] = *(const bf16x8*)(&pool[0][1][o]);
                fq2[kc] = *(const bf16x8*)(&pool[0][2][o]);
            }
        }
    }

    const f32x4 zero4 = {0.f, 0.f, 0.f, 0.f};
    float lsum[4];
#pragma unroll
    for (int r = 0; r < 4; r++) lsum[r] = 0.f;

    // ---- pass A: denominator; dbuf pipeline, 1 barrier/jt, frag-linear reads ----
    int cur = 0;
    {   // prologue: stage tile 0 into pool[0]
        const float* src = kg0 + sr * 64 + sd;
        const float4 fA = *(const float4*)(src);
        const float4 fB = *(const float4*)(src + 4);
        __syncthreads();                    // Q-frag reads of pool[0] complete
        const float xv[8] = {fA.x, fA.y, fA.z, fA.w, fB.x, fB.y, fB.z, fB.w};
        u16 a0[8], a1[8], a2[8];
#pragma unroll
        for (int j = 0; j < 8; j++) split3t(xv[j], a0[j], a1[j], a2[j]);
        int4 p0, p1, p2;
        p0.x = a0[0] | (a0[1] << 16); p0.y = a0[2] | (a0[3] << 16);
        p0.z = a0[4] | (a0[5] << 16); p0.w = a0[6] | (a0[7] << 16);
        p1.x = a1[0] | (a1[1] << 16); p1.y = a1[2] | (a1[3] << 16);
        p1.z = a1[4] | (a1[5] << 16); p1.w = a1[6] | (a1[7] << 16);
        p2.x = a2[0] | (a2[1] << 16); p2.y = a2[2] | (a2[3] << 16);
        p2.z = a2[4] | (a2[5] << 16); p2.w = a2[6] | (a2[7] << 16);
        *(int4*)(&pool[0][0][sdst]) = p0;
        *(int4*)(&pool[0][1][sdst]) = p1;
        *(int4*)(&pool[0][2][sdst]) = p2;
        __syncthreads();
    }

    for (int jt = 0; jt < 32; jt++) {
        // issue next tile's loads — consumed by the ds_write below (same
        // inter-barrier region); latency hides under the MFMA+exp block.
        const int jn = (jt + 1 < 32) ? jt + 1 : 31;
        const float* src = kg0 + (size_t)jn * 4096 + sr * 64 + sd;
        const float4 fA = *(const float4*)(src);
        const float4 fB = *(const float4*)(src + 4);

        // compute from pool[cur] — all reads are base + l*16B (conflict-free)
        const u16* K0c = pool[cur][0];
        const u16* K1c = pool[cur][1];
        const u16* K2c = pool[cur][2];
        float tmax = -1e30f;
#pragma unroll
        for (int nt = 0; nt < 4; nt++) {
            f32x4 aHH = zero4, aC = zero4;
#pragma unroll
            for (int kc = 0; kc < 2; kc++) {
                const int ko = (((nt << 1) + kc) << 9) + l * 8;
                const bf16x8 k0 = *(const bf16x8*)(&K0c[ko]);
                const bf16x8 k1 = *(const bf16x8*)(&K1c[ko]);
                const bf16x8 k2 = *(const bf16x8*)(&K2c[ko]);
                aHH = __builtin_amdgcn_mfma_f32_16x16x32_bf16(fq0[kc], k0, aHH, 0, 0, 0);
                aC  = __builtin_amdgcn_mfma_f32_16x16x32_bf16(fq0[kc], k1, aC, 0, 0, 0);
                aC  = __builtin_amdgcn_mfma_f32_16x16x32_bf16(fq1[kc], k0, aC, 0, 0, 0);
                aC  = __builtin_amdgcn_mfma_f32_16x16x32_bf16(fq1[kc], k1, aC, 0, 0, 0);
                aC  = __builtin_amdgcn_mfma_f32_16x16x32_bf16(fq0[kc], k2, aC, 0, 0, 0);
                aC  = __builtin_amdgcn_mfma_f32_16x16x32_bf16(fq2[kc], k0, aC, 0, 0, 0);
            }
#pragma unroll
            for (int r = 0; r < 4; r++) {
                const float s = fminf(fmaxf(aHH[r] + aC[r], -30.f), 30.f);
                tmax = fmaxf(tmax, s);
                lsum[r] += __expf(s);
            }
        }
        // wave-tile max of ACCURATE scores (read by same wave in pass B)
#pragma unroll
        for (int off = 1; off < 64; off <<= 1)
            tmax = fmaxf(tmax, __shfl_xor(tmax, off, 64));
        if (l == 0) smaxL[w][jt] = tmax;

        // stage next tile into pool[cur^1] (disjoint from all pool[cur] readers)
        {
            const float xv[8] = {fA.x, fA.y, fA.z, fA.w, fB.x, fB.y, fB.z, fB.w};
            u16 a0[8], a1[8], a2[8];
#pragma unroll
            for (int j = 0; j < 8; j++) split3t(xv[j], a0[j], a1[j], a2[j]);
            int4 p0, p1, p2;
            p0.x = a0[0] | (a0[1] << 16); p0.y = a0[2] | (a0[3] << 16);
            p0.z = a0[4] | (a0[5] << 16); p0.w = a0[6] | (a0[7] << 16);
            p1.x = a1[0] | (a1[1] << 16); p1.y = a1[2] | (a1[3] << 16);
            p1.z = a1[4] | (a1[5] << 16); p1.w = a1[6] | (a1[7] << 16);
            p2.x = a2[0] | (a2[1] << 16); p2.y = a2[2] | (a2[3] << 16);
            p2.z = a2[4] | (a2[5] << 16); p2.w = a2[6] | (a2[7] << 16);
            *(int4*)(&pool[cur ^ 1][0][sdst]) = p0;
            *(int4*)(&pool[cur ^ 1][1][sdst]) = p1;
            *(int4*)(&pool[cur ^ 1][2][sdst]) = p2;
        }
        __syncthreads();   // publishes pool[cur^1]; all pool[cur] reads already done
        cur ^= 1;
    }

#pragma unroll
    for (int r = 0; r < 4; r++) {
#pragma unroll
        for (int off = 1; off < 16; off <<= 1)
            lsum[r] += __shfl_xor(lsum[r], off, 64);
    }
    double l_d[4]; float inv_l[4];
#pragma unroll
    for (int r = 0; r < 4; r++) {
        l_d[r] = (double)lsum[r];
        inv_l[r] = 1.0f / lsum[r];
    }

    // skip threshold: tile all-zero iff smax < ln(0.0085 * min-row-Z)
    float zmin4 = fminf(fminf(lsum[0], lsum[1]), fminf(lsum[2], lsum[3]));
    zmin4 = fminf(zmin4, __shfl_xor(zmin4, 16, 64));
    zmin4 = fminf(zmin4, __shfl_xor(zmin4, 32, 64));
    const float sthr = logf(0.0085f * zmin4);

    f32x4 oacc[4];
#pragma unroll
    for (int dt = 0; dt < 4; dt++) oacc[dt] = zero4;

    // ---- pass B: dbuf; K-hi=pool[cur][0], V=pool[cur][1], P=pool[0..1][2] ----
    // staging: thread t reads one int4 (=one chunk's data) coalesced from global
    // and scatters it to its fragment chunk.
    const int rB = t >> 3, cB = (t & 7) * 8;
    const int chB8 = (((rB >> 4) * 2 + (cB >> 5)) * 64 + (((cB >> 3) & 3) << 4) + (rB & 15)) * 8;
    u16* const Pw = &pool[w >> 2][2][(w & 3) * 1024];

    {   // prologue: stage tile 0 (pass-A reads completed before its last barrier)
        const int4 kb0 = *(const int4*)(&kh0[(size_t)rB * HD + cB]);
        const int4 vr0 = *(const int4*)(&vb[(size_t)rB * S_ + cB]);
        *(int4*)(&pool[0][0][chB8]) = kb0;
        *(int4*)(&pool[0][1][chB8]) = vr0;
        __syncthreads();
    }
    cur = 0;

    for (int jt = 0; jt < 32; jt++) {
        // issue next tile's loads — consumed by ds_write below, before barrier 1
        const int jn = (jt + 1 < 32) ? jt + 1 : 31;
        const int4 kb = *(const int4*)(&kh0[(size_t)jn * 4096 + (size_t)rB * HD + cB]);
        const int4 vr = *(const int4*)(&vb[(size_t)rB * S_ + jn * 64 + cB]);

        const bool live = (smaxL[w][jt] >= sthr);   // wave-uniform branch

        if (live) {
            const u16* Kc = pool[cur][0];
#pragma unroll
            for (int nt = 0; nt < 4; nt++) {
                f32x4 sacc = zero4;
#pragma unroll
                for (int kc = 0; kc < 2; kc++) {
                    const bf16x8 k0 = *(const bf16x8*)(&Kc[(((nt << 1) + kc) << 9) + l * 8]);
                    sacc = __builtin_amdgcn_mfma_f32_16x16x32_bf16(fq0[kc], k0, sacc, 0, 0, 0);
                }
#pragma unroll
                for (int r = 0; r < 4; r++) {
                    const float s = fminf(fmaxf(sacc[r], -30.f), 30.f);
                    const float p = __expf(s) * inv_l[r];
                    u16 pb;
                    if (p > 0.0115f) {
                        pb = f2bf(p);
                    } else if (p < 0.009f) {
                        pb = 0;
                    } else {
                        const int row = q0 + w * 16 + lq * 4 + r;
                        const int col = jt * 64 + nt * 16 + lr;
                        const float* qr  = q_ws + ((size_t)bh * S_ + row) * HD;
                        const float* kcv = k_ws + ((size_t)bh * S_ + col) * HD;
                        double s64 = 0.0;
                        for (int d = 0; d < HD; d++) s64 += (double)qr[d] * (double)kcv[d];
                        s64 = fmin(fmax(s64 * 0.125, -30.0), 30.0);
                        const double pd = exp(s64) / l_d[r];
                        pb = (pd > 0.01) ? f2bf((float)pd) : (u16)0;
                    }
                    // P in fragment-linear form: value at (q-row lq*4+r, key nt*16+lr)
                    const int key = nt * 16 + lr;
                    const int pAddr = (((key >> 5) << 6) + (((key >> 3) & 3) << 4) + (lq * 4 + r)) * 8
                                    + (key & 7);
                    Pw[pAddr] = pb;
                }
            }
        }
        // stage next tile into pool[cur^1] (disjoint from score reads of pool[cur])
        *(int4*)(&pool[cur ^ 1][0][chB8]) = kb;
        *(int4*)(&pool[cur ^ 1][1][chB8]) = vr;
        __syncthreads();   // P fence + publishes staged tile
        if (live) {
            const u16* Vc = pool[cur][1];
#pragma unroll
            for (int kc = 0; kc < 2; kc++) {
                const bf16x8 ap = *(const bf16x8*)(&Pw[(kc << 9) + l * 8]);
#pragma unroll
                for (int dt = 0; dt < 4; dt++) {
                    const bf16x8 bv = *(const bf16x8*)(&Vc[(((dt << 1) + kc) << 9) + l * 8]);
                    oacc[dt] = __builtin_amdgcn_mfma_f32_16x16x32_bf16(ap, bv, oacc[dt], 0, 0, 0);
                }
            }
        }
        __syncthreads();   // PV reads of pool[cur] / P done before next overwrite
        cur ^= 1;
    }

    // epilogue
#pragma unroll
    for (int dt = 0; dt < 4; dt++) {
#pragma unroll
        for (int r = 0; r < 4; r++) {
            const int row = q0 + w * 16 + lq * 4 + r;
            const int d   = dt * 16 + lr;
            ao_ws[((size_t)b * S_ + row) * DM + h * HD + d] = f2bf(oacc[dt][r]);
        }
    }
}

// ---------------- out projection: MFMA, bf16 A x 2-split W^T -> fp32 out ----------------
__global__ __launch_bounds__(256) void gemm_out_mfma(
    const u16* __restrict__ A, const u16* __restrict__ Wt0, const u16* __restrict__ Wt1,
    const float* __restrict__ bias, float* __restrict__ out)
{
    __shared__ __attribute__((aligned(16))) u16 As[128 * 32];
    __shared__ __attribute__((aligned(16))) u16 Bs0[128 * 32], Bs1[128 * 32];

    const int t  = threadIdx.x;
    const int m0 = blockIdx.y * 128, n0 = blockIdx.x * 128;
    const int w  = t >> 6, l = t & 63;
    const int wm = (w >> 1) * 64, wn = (w & 1) * 64;
    const int lr = l & 15, lq = l >> 4;

    const f32x4 zero4 = {0.f, 0.f, 0.f, 0.f};
    f32x4 acc[4][4];
#pragma unroll
    for (int i = 0; i < 4; i++)
#pragma unroll
        for (int j = 0; j < 4; j++) acc[i][j] = zero4;

    for (int k0 = 0; k0 < 512; k0 += 32) {
        __syncthreads();
#pragma unroll
        for (int i = 0; i < 2; i++) {
            const int e = t + 256 * i;
            const int r = e >> 2, c0 = (e & 3) * 8;
            *(int4*)(&As[r * 32 + c0])  = *(const int4*)(&A  [(size_t)(m0 + r) * 512 + k0 + c0]);
            *(int4*)(&Bs0[r * 32 + c0]) = *(const int4*)(&Wt0[(size_t)(n0 + r) * 512 + k0 + c0]);
            *(int4*)(&Bs1[r * 32 + c0]) = *(const int4*)(&Wt1[(size_t)(n0 + r) * 512 + k0 + c0]);
        }
        __syncthreads();

#pragma unroll
        for (int i = 0; i < 4; i++) {
            const bf16x8 a = *(const bf16x8*)(&As[(wm + i * 16 + lr) * 32 + lq * 8]);
#pragma unroll
            for (int j = 0; j < 4; j++) {
                const int bo = (wn + j * 16 + lr) * 32 + lq * 8;
                const bf16x8 b0 = *(const bf16x8*)(&Bs0[bo]);
                const bf16x8 b1 = *(const bf16x8*)(&Bs1[bo]);
                f32x4 c = acc[i][j];
                c = __builtin_amdgcn_mfma_f32_16x16x32_bf16(a, b0, c, 0, 0, 0);
                c = __builtin_amdgcn_mfma_f32_16x16x32_bf16(a, b1, c, 0, 0, 0);
                acc[i][j] = c;
            }
        }
    }

#pragma unroll
    for (int j = 0; j < 4; j++) {
        const int n = n0 + wn + j * 16 + lr;
        const float bv = bias[n];
#pragma unroll
        for (int i = 0; i < 4; i++) {
#pragma unroll
            for (int r = 0; r < 4; r++) {
                const int m = m0 + wm + i * 16 + lq * 4 + r;
                out[(size_t)m * 512 + n] = acc[i][j][r] + bv;
            }
        }
    }
}

// ---------------- launch ----------------
extern "C" void kernel_launch(void* const* d_in, const int* in_sizes, int n_in,
                              void* d_out, int out_size, void* d_ws, size_t ws_size,
                              hipStream_t stream) {
    const float* x = nullptr; const float* Wqkv = nullptr; const float* bqkv = nullptr;
    const float* Wout = nullptr; const float* bout = nullptr;
    for (int i = 0; i < n_in; i++) {
        switch (in_sizes[i]) {
            case 4194304: x    = (const float*)d_in[i]; break;
            case 786432:  Wqkv = (const float*)d_in[i]; break;
            case 1536:    bqkv = (const float*)d_in[i]; break;
            case 262144:  Wout = (const float*)d_in[i]; break;
            case 512:     bout = (const float*)d_in[i]; break;
            default: break;
        }
    }
    if (!x)    x    = (const float*)d_in[0];
    if (!Wqkv) Wqkv = (const float*)d_in[1];
    if (!bqkv) bqkv = (const float*)d_in[2];
    if (!Wout) Wout = (const float*)d_in[3];
    if (!bout) bout = (const float*)d_in[4];

    float* out = (float*)d_out;

    // Layout (48 MB ws): q 0-16 | k 16-32 | vt 32-40 | ao 40-48
    // khi (RNE bf16 K, 8 MB) lives in d_out scratch — dead until gemm_out
    // fully overwrites it at the end (stream-ordered).
    char* ws = (char*)d_ws;
    float* q_ws  = (float*)(ws);
    float* k_ws  = (float*)(ws + (16ull << 20));
    u16* vt_ws = (u16*)(ws + (32ull << 20));
    u16* ao_ws = (u16*)(ws + (40ull << 20));
    u16* khi_ws = (u16*)d_out;                             // 8 MB of the 16 MB out buf
    u16* wt0 = (u16*)(ws + (40ull << 20));                 // ao region, dead pre-attn
    u16* wt1 = (u16*)(ws + (40ull << 20) + 1572864);
    u16* wt2 = (u16*)(ws + (40ull << 20) + 3145728);
    u16* wo0 = (u16*)(ws + (32ull << 20));                 // vt region, dead post-attn
    u16* wo1 = (u16*)(ws + (32ull << 20) + 524288);

    prep_split_wT<<<3072, 256, 0, stream>>>(Wqkv, 1536, 1536 * 512, wt0, wt1, wt2);
    gemm_qkv_mfma<<<dim3(12, 64), 256, 0, stream>>>(
        x, wt0, wt1, wt2, bqkv, q_ws, k_ws, khi_ws, vt_ws);
    attn_mfma128<<<dim3(16, BHN), 512, 0, stream>>>(q_ws, k_ws, khi_ws, vt_ws, ao_ws);
    prep_split_wT<<<1024, 256, 0, stream>>>(Wout, 512, 512 * 512, wo0, wo1, nullptr);
    gemm_out_mfma<<<dim3(4, 64), 256, 0, stream>>>(ao_ws, wo0, wo1, bout, out);
}